// Round 7
// baseline (128.323 us; speedup 1.0000x reference)
//
#include <hip/hip_runtime.h>
#include <hip/hip_bf16.h>

// SelfAttentionHead: EMB=1024, KEY=HEAD=64, B=4, T=4096
#define EMB 1024
#define NB  4
#define TT  4096
#define DD  64

// fold 1/sqrt(64) and log2(e) into Q so softmax runs in exp2 domain
static constexpr float SCALE2 = 0.125f * 1.4426950408889634f;

typedef __bf16          bfrag    __attribute__((ext_vector_type(8)));
typedef float           f32x4    __attribute__((ext_vector_type(4)));
typedef unsigned short  ushort8t __attribute__((ext_vector_type(8)));
typedef unsigned short  ushort4t __attribute__((ext_vector_type(4)));
typedef unsigned int    uint32;
typedef uint32          uint32x4 __attribute__((ext_vector_type(4)));

__device__ __forceinline__ unsigned short f2bf(float f) {
    __hip_bfloat16 h = __float2bfloat16(f);   // RNE
    return __builtin_bit_cast(unsigned short, h);
}
__device__ __forceinline__ float bf2f(unsigned short u) {
    uint32 v = ((uint32)u) << 16;
    return __builtin_bit_cast(float, v);
}
__device__ __forceinline__ uint32 pk2(float a, float b) {
    return (uint32)f2bf(a) | ((uint32)f2bf(b) << 16);
}

// ---------------------------------------------------------------------------
// Prep (round-4 proven): Wt[n][k] bf16, n in [0,192) = concat(Wk, Wq*SCALE2,
// Wv) columns; k contiguous (linear, unswizzled).
// ---------------------------------------------------------------------------
__global__ __launch_bounds__(256) void prep_wt(
    const float* __restrict__ Wk, const float* __restrict__ Wq,
    const float* __restrict__ Wv, unsigned short* __restrict__ Wt)
{
    const int o = blockIdx.x * 256 + threadIdx.x;   // 0 .. 192*1024-1
    const int n = o >> 10, k = o & 1023;
    float v;
    if (n < 64)       v = Wk[k * 64 + n];
    else if (n < 128) v = Wq[k * 64 + (n - 64)] * SCALE2;
    else              v = Wv[k * 64 + (n - 128)];
    Wt[o] = f2bf(v);
}

// ---------------------------------------------------------------------------
// QKV projection (round-4 proven): bf16 MFMA GEMM, M-tile 64, 4 waves, T14
// reg-prefetch of next k-step's emb/W tiles. Outputs Q/K bf16 row-major
// (Q pre-scaled), V^T [b][h][t].
// ---------------------------------------------------------------------------
#define PSTR 66

__global__ __launch_bounds__(256) void qkv_mfma(
    const float* __restrict__ emb,
    const unsigned short* __restrict__ Wt,
    const float* __restrict__ bk, const float* __restrict__ bq,
    const float* __restrict__ bv,
    unsigned short* __restrict__ Qb, unsigned short* __restrict__ Kb,
    unsigned short* __restrict__ Vt)
{
    __shared__ unsigned short elds[64 * PSTR];
    __shared__ unsigned short wlds[192 * PSTR];

    const int tid = threadIdx.x;
    const int w = tid >> 6, l = tid & 63;
    const int lr = l & 15, lg = l >> 4;
    const int m0 = blockIdx.x * 64;

    f32x4 acc[12];
#pragma unroll
    for (int i = 0; i < 12; ++i) acc[i] = (f32x4){0.f, 0.f, 0.f, 0.f};

    const int er = tid >> 2, ec = (tid & 3) * 16;

    float4 f0, f1, f2, f3;
    ushort8t wr[6];
    {   // prologue: load k0 = 0 tiles into regs
        const float* src = emb + (size_t)(m0 + er) * EMB + ec;
        f0 = *(const float4*)(src + 0);
        f1 = *(const float4*)(src + 4);
        f2 = *(const float4*)(src + 8);
        f3 = *(const float4*)(src + 12);
#pragma unroll
        for (int i = 0; i < 6; ++i) {
            const int idx = tid + i * 256;
            const int row = idx >> 3, c = (idx & 7) * 8;
            wr[i] = *(const ushort8t*)&Wt[(size_t)row * 1024 + c];
        }
    }

    for (int it = 0; it < 16; ++it) {
        __syncthreads();   // previous iteration's MFMA reads are done
        {   // write staged regs -> LDS (f32 -> bf16 for emb)
            ushort8t lo, hi;
            lo[0]=f2bf(f0.x); lo[1]=f2bf(f0.y); lo[2]=f2bf(f0.z); lo[3]=f2bf(f0.w);
            lo[4]=f2bf(f1.x); lo[5]=f2bf(f1.y); lo[6]=f2bf(f1.z); lo[7]=f2bf(f1.w);
            hi[0]=f2bf(f2.x); hi[1]=f2bf(f2.y); hi[2]=f2bf(f2.z); hi[3]=f2bf(f2.w);
            hi[4]=f2bf(f3.x); hi[5]=f2bf(f3.y); hi[6]=f2bf(f3.z); hi[7]=f2bf(f3.w);
            *(ushort8t*)&elds[er * PSTR + ec]     = lo;
            *(ushort8t*)&elds[er * PSTR + ec + 8] = hi;
#pragma unroll
            for (int i = 0; i < 6; ++i) {
                const int idx = tid + i * 256;
                const int row = idx >> 3, c = (idx & 7) * 8;
                *(ushort8t*)&wlds[row * PSTR + c] = wr[i];
            }
        }
        // prefetch next k-step into regs (completes under the MFMA phase)
        if (it < 15) {
            const int kn = (it + 1) * 64;
            const float* src = emb + (size_t)(m0 + er) * EMB + kn + ec;
            f0 = *(const float4*)(src + 0);
            f1 = *(const float4*)(src + 4);
            f2 = *(const float4*)(src + 8);
            f3 = *(const float4*)(src + 12);
#pragma unroll
            for (int i = 0; i < 6; ++i) {
                const int idx = tid + i * 256;
                const int row = idx >> 3, c = (idx & 7) * 8;
                wr[i] = *(const ushort8t*)&Wt[(size_t)row * 1024 + kn + c];
            }
        }
        __syncthreads();
#pragma unroll
        for (int c = 0; c < 2; ++c) {
            bfrag a = *(const bfrag*)&elds[(w * 16 + lr) * PSTR + c * 32 + lg * 8];
#pragma unroll
            for (int nt = 0; nt < 12; ++nt) {
                bfrag bb = *(const bfrag*)&wlds[(nt * 16 + lr) * PSTR + c * 32 + lg * 8];
                acc[nt] = __builtin_amdgcn_mfma_f32_16x16x32_bf16(a, bb, acc[nt], 0, 0, 0);
            }
        }
    }

    const int rbase = m0 + w * 16 + lg * 4;
#pragma unroll
    for (int nt = 0; nt < 12; ++nt) {
        const int n = nt * 16 + lr;
        float bias;
        if (n < 64)       bias = bk[n];
        else if (n < 128) bias = bq[n - 64] * SCALE2;
        else              bias = bv[n - 128];
        if (nt < 8) {
            unsigned short* dst = (nt < 4) ? Kb : Qb;
            const int d = (nt < 4) ? n : (n - 64);
#pragma unroll
            for (int rg = 0; rg < 4; ++rg)
                dst[(size_t)(rbase + rg) * 64 + d] = f2bf(acc[nt][rg] + bias);
        } else {
            const int h = n - 128;
            const int b = rbase >> 12, t = rbase & (TT - 1);
            ushort4t pk;
#pragma unroll
            for (int rg = 0; rg < 4; ++rg) pk[rg] = f2bf(acc[nt][rg] + bias);
            *(ushort4t*)&Vt[((size_t)b * 64 + h) * TT + t] = pk;
        }
    }
}

// ---------------------------------------------------------------------------
// Flash attention partials: 1-wave blocks, ZERO LDS, no barriers, split-K.
// Swapped QK^T (S^T = mfma(K,Q)); P redistribution for the PV A-operand is
// fully in-register. Mapping (verified on concrete lanes):
//   dest lane (lr,g), dword w2, block cc needs source word
//       pw[4cc + 2*(g>>1) + (w2&1)]  from lane  lr + 16*(2*(g&1)+(w2>>1)).
//   Dests of BOTH halves (g>>1 = 0 and 1) pull from the same source lane,
//   so ONE bpermute cannot serve both (round-5/6 bug). Fix: two bpermutes
//   (lo/hi word) + select by the DEST's half (ghi).
// ---------------------------------------------------------------------------
__global__ __launch_bounds__(64, 4) void attn_part(
    const unsigned short* __restrict__ Qb,
    const unsigned short* __restrict__ Kb,
    const unsigned short* __restrict__ Vt,
    unsigned short* __restrict__ po, float* __restrict__ pml,
    int chunk, int nch)
{
    const int idx  = blockIdx.x;
    const int c    = idx >> 9;                    // chunk layer
    const int b    = idx & 3;
    const int ti32 = 127 - ((idx >> 2) & 127);    // heavy-first
    const int nkt  = (ti32 >> 1) + 1;
    const int kt0  = c * chunk;
    if (kt0 >= nkt) return;
    const int kt1 = min(nkt, kt0 + chunk);

    const int l  = threadIdx.x;
    const int lr = l & 15, g = l >> 4;
    const int q0 = ti32 * 32;
    const size_t bTT = (size_t)b * TT;

    // Q fragments (B-operand): lane holds Q[q0+s*16+lr][k=g*8..+7]
    bfrag qa[2][2];
#pragma unroll
    for (int s = 0; s < 2; ++s) {
        const size_t qr = (bTT + q0 + s * 16 + lr) * 64 + g * 8;
        qa[s][0] = *(const bfrag*)&Qb[qr];
        qa[s][1] = *(const bfrag*)&Qb[qr + 32];
    }

    // hoisted pointers (elements); advance by constants per tile
    const unsigned short* kpA = Kb + (bTT + (size_t)kt0 * 64 + lr) * 64 + g * 8;
    const unsigned short* kpB = kpA + 2048;            // nt = 2,3 base
    const unsigned short* vp0 = Vt + ((size_t)b * 64 +  0 + lr) * TT + (size_t)kt0 * 64 + g * 8;
    const unsigned short* vp1 = vp0 + 16 * TT;
    const unsigned short* vp2 = vp0 + 32 * TT;
    const unsigned short* vp3 = vp0 + 48 * TT;

    // bpermute lane addresses (bytes): w2<2 -> lane lr+32*(g&1); w2>=2 -> +16
    const int addr_a = (lr + 32 * (g & 1)) * 4;
    const int addr_b = addr_a + 64;
    const bool ghi = (g >= 2);

    f32x4 o[2][4];
#pragma unroll
    for (int s = 0; s < 2; ++s)
#pragma unroll
        for (int ht = 0; ht < 4; ++ht) o[s][ht] = (f32x4){0.f, 0.f, 0.f, 0.f};
    float mrow[2] = {-1e30f, -1e30f};
    float lrow[2] = {0.f, 0.f};

    for (int kt = kt0; kt < kt1; ++kt) {
        // K fragments (A-operand): K[key=k0+nt*16+lr][k=g*8..]
        bfrag kf[4][2];
        kf[0][0] = *(const bfrag*)(kpA +    0);
        kf[0][1] = *(const bfrag*)(kpA +   32);
        kf[1][0] = *(const bfrag*)(kpA + 1024);
        kf[1][1] = *(const bfrag*)(kpA + 1056);
        kf[2][0] = *(const bfrag*)(kpB +    0);
        kf[2][1] = *(const bfrag*)(kpB +   32);
        kf[3][0] = *(const bfrag*)(kpB + 1024);
        kf[3][1] = *(const bfrag*)(kpB + 1056);
        // V fragments (B-operand for PV): V^T[h=ht*16+lr][k0+cc*32+g*8..]
        bfrag vf[4][2];
        vf[0][0] = *(const bfrag*)(vp0);  vf[0][1] = *(const bfrag*)(vp0 + 32);
        vf[1][0] = *(const bfrag*)(vp1);  vf[1][1] = *(const bfrag*)(vp1 + 32);
        vf[2][0] = *(const bfrag*)(vp2);  vf[2][1] = *(const bfrag*)(vp2 + 32);
        vf[3][0] = *(const bfrag*)(vp3);  vf[3][1] = *(const bfrag*)(vp3 + 32);

        const bool diag = (kt == nkt - 1);
        const int  k0   = kt * 64;

#pragma unroll
        for (int s = 0; s < 2; ++s) {
            // S^T: lane (lr,g) reg rg = S[q0+s*16+lr][k0+nt*16+4g+rg]
            f32x4 sv[4];
#pragma unroll
            for (int nt = 0; nt < 4; ++nt) {
                sv[nt] = (f32x4){0.f, 0.f, 0.f, 0.f};
                sv[nt] = __builtin_amdgcn_mfma_f32_16x16x32_bf16(kf[nt][0], qa[s][0], sv[nt], 0, 0, 0);
                sv[nt] = __builtin_amdgcn_mfma_f32_16x16x32_bf16(kf[nt][1], qa[s][1], sv[nt], 0, 0, 0);
            }
            const int qrow = q0 + s * 16 + lr;
            if (diag) {
#pragma unroll
                for (int nt = 0; nt < 4; ++nt)
#pragma unroll
                    for (int rg = 0; rg < 4; ++rg) {
                        const int key = k0 + nt * 16 + 4 * g + rg;
                        if (key > qrow) sv[nt][rg] = -1e30f;
                    }
            }
            // row max over 16 regs + lanes lr+16k
            float pm = fmaxf(fmaxf(fmaxf(sv[0][0], sv[0][1]), fmaxf(sv[0][2], sv[0][3])),
                             fmaxf(fmaxf(sv[1][0], sv[1][1]), fmaxf(sv[1][2], sv[1][3])));
            pm = fmaxf(pm, fmaxf(fmaxf(fmaxf(sv[2][0], sv[2][1]), fmaxf(sv[2][2], sv[2][3])),
                                 fmaxf(fmaxf(sv[3][0], sv[3][1]), fmaxf(sv[3][2], sv[3][3]))));
            pm = fmaxf(pm, __shfl_xor(pm, 16));
            pm = fmaxf(pm, __shfl_xor(pm, 32));

            // defer-max (T13)
            if (!__all(pm - mrow[s] <= 8.0f)) {
                const float nm = fmaxf(mrow[s], pm);
                const float cr = exp2f(mrow[s] - nm);
                mrow[s] = nm;
                lrow[s] *= cr;
#pragma unroll
                for (int ht = 0; ht < 4; ++ht) o[s][ht] *= cr;
            }

            // P = exp2(S - m) packed bf16 pairs + row sum
            float ls = 0.f;
            uint32 pw[8];
#pragma unroll
            for (int nt = 0; nt < 4; ++nt)
#pragma unroll
                for (int h = 0; h < 2; ++h) {
                    const float pa_ = exp2f(sv[nt][2 * h]     - mrow[s]);
                    const float pb_ = exp2f(sv[nt][2 * h + 1] - mrow[s]);
                    ls += pa_ + pb_;
                    pw[nt * 2 + h] = pk2(pa_, pb_);
                }
            ls += __shfl_xor(ls, 16);
            ls += __shfl_xor(ls, 32);
            lrow[s] += ls;

            // in-register P redistribution -> A-frags (dual bpermute + dest
            // select), then PV
#pragma unroll
            for (int cc = 0; cc < 2; ++cc) {
                uint32x4 dw;
#pragma unroll
                for (int w2 = 0; w2 < 4; ++w2) {
                    const int addr = (w2 < 2) ? addr_a : addr_b;
                    const uint32 lo = (uint32)__builtin_amdgcn_ds_bpermute(
                        addr, (int)pw[4 * cc + (w2 & 1)]);
                    const uint32 hi = (uint32)__builtin_amdgcn_ds_bpermute(
                        addr, (int)pw[4 * cc + 2 + (w2 & 1)]);
                    dw[w2] = ghi ? hi : lo;
                }
                const bfrag pa = __builtin_bit_cast(bfrag, dw);
                o[s][0] = __builtin_amdgcn_mfma_f32_16x16x32_bf16(pa, vf[0][cc], o[s][0], 0, 0, 0);
                o[s][1] = __builtin_amdgcn_mfma_f32_16x16x32_bf16(pa, vf[1][cc], o[s][1], 0, 0, 0);
                o[s][2] = __builtin_amdgcn_mfma_f32_16x16x32_bf16(pa, vf[2][cc], o[s][2], 0, 0, 0);
                o[s][3] = __builtin_amdgcn_mfma_f32_16x16x32_bf16(pa, vf[3][cc], o[s][3], 0, 0, 0);
            }
        }
        kpA += 4096; kpB += 4096;
        vp0 += 64; vp1 += 64; vp2 += 64; vp3 += 64;
    }

    // store partials: po coded C-layout bf16 (coalesced), pml (m,l) f32
    const int slot = (((b << 7) + ti32) * nch) + c;
    const size_t pob = (size_t)slot * 2048;
#pragma unroll
    for (int s = 0; s < 2; ++s)
#pragma unroll
        for (int ht = 0; ht < 4; ++ht)
#pragma unroll
            for (int rg = 0; rg < 4; ++rg)
                po[pob + (size_t)(((s * 4 + ht) * 4 + rg) * 64 + l)] = f2bf(o[s][ht][rg]);
    if (g == 0) {
#pragma unroll
        for (int s = 0; s < 2; ++s) {
            pml[slot * 64 + s * 16 + lr]      = mrow[s];
            pml[slot * 64 + 32 + s * 16 + lr] = lrow[s];
        }
    }
}

// ---------------------------------------------------------------------------
// Merge split-K partials. grid = 512 (one per (b, ti32)), 256 threads; each
// thread owns 8 coded elements (same row, 8 consecutive cols).
// ---------------------------------------------------------------------------
__global__ __launch_bounds__(256) void attn_merge(
    const unsigned short* __restrict__ po, const float* __restrict__ pml,
    float* __restrict__ out, int chunk, int nch)
{
    const int idx  = blockIdx.x;      // 0..511
    const int b    = idx & 3;
    const int ti32 = idx >> 2;
    const int nkt  = (ti32 >> 1) + 1;
    const int nc   = (nkt + chunk - 1) / chunk;

    const int e0   = threadIdx.x * 8;
    const int lane = e0 & 63;
    const int rg   = (e0 >> 6) & 3;
    const int ht   = (e0 >> 8) & 3;
    const int s    = e0 >> 10;
    const int row  = s * 16 + ((lane >> 4) << 2) + rg;
    const int col0 = ht * 16 + (lane & 15);
    const int slot0 = ((b << 7) + ti32) * nch;

    float M = -1e30f;
    for (int c = 0; c < nc; ++c)
        M = fmaxf(M, pml[(slot0 + c) * 64 + row]);

    float den = 0.f;
    float acc[8];
#pragma unroll
    for (int i = 0; i < 8; ++i) acc[i] = 0.f;

    for (int c = 0; c < nc; ++c) {
        const float wgt = exp2f(pml[(slot0 + c) * 64 + row] - M);
        den += wgt * pml[(slot0 + c) * 64 + 32 + row];
        const ushort8t v = *(const ushort8t*)&po[(size_t)(slot0 + c) * 2048 + e0];
#pragma unroll
        for (int j = 0; j < 8; ++j) acc[j] += wgt * bf2f(v[j]);
    }
    const float inv = 1.0f / den;
    float* dst = out + ((size_t)b * TT + ti32 * 32 + row) * 64 + col0;
    float4 o0 = {acc[0] * inv, acc[1] * inv, acc[2] * inv, acc[3] * inv};
    float4 o1 = {acc[4] * inv, acc[5] * inv, acc[6] * inv, acc[7] * inv};
    *(float4*)(dst)     = o0;
    *(float4*)(dst + 4) = o1;
}

// ---------------------------------------------------------------------------
extern "C" void kernel_launch(void* const* d_in, const int* in_sizes, int n_in,
                              void* d_out, int out_size, void* d_ws, size_t ws_size,
                              hipStream_t stream)
{
    const float* emb = (const float*)d_in[0];
    const float* Wk  = (const float*)d_in[1];
    const float* bk  = (const float*)d_in[2];
    const float* Wq  = (const float*)d_in[3];
    const float* bq  = (const float*)d_in[4];
    const float* Wv  = (const float*)d_in[5];
    const float* bv  = (const float*)d_in[6];
    float* out = (float*)d_out;

    // ws: Qb[2MB] Kb[2MB] Vt[2MB] Wt[384KB] | po (bf16) | pml (f32)
    char* base = (char*)d_ws;
    unsigned short* Qb = (unsigned short*)(base);
    unsigned short* Kb = (unsigned short*)(base + (2u << 20));
    unsigned short* Vt = (unsigned short*)(base + (4u << 20));
    unsigned short* Wt = (unsigned short*)(base + (6u << 20));
    const size_t pbase = ((size_t)6 << 20) + (512u << 10);   // 6.5 MB

    int nch = 8;
    for (;;) {
        const size_t need = pbase +
            (size_t)512 * nch * (2048 * sizeof(unsigned short) + 64 * sizeof(float));
        if (need <= ws_size || nch == 1) break;
        nch >>= 1;
    }
    const int chunk = 64 / nch;
    unsigned short* po = (unsigned short*)(base + pbase);
    float* pml = (float*)(po + (size_t)512 * nch * 2048);

    prep_wt<<<192 * 1024 / 256, 256, 0, stream>>>(Wk, Wq, Wv, Wt);
    qkv_mfma<<<(NB * TT) / 64, 256, 0, stream>>>(emb, Wt, bk, bq, bv, Qb, Kb, Vt);
    attn_part<<<512 * nch, 64, 0, stream>>>(Qb, Kb, Vt, po, pml, chunk, nch);
    attn_merge<<<512, 256, 0, stream>>>(po, pml, out, chunk, nch);
}

// Round 8
// 87.002 us; speedup vs baseline: 1.4750x; 1.4750x over previous
//
#include <hip/hip_runtime.h>
#include <hip/hip_bf16.h>

// SelfAttentionHead: EMB=1024, KEY=HEAD=64, B=4, T=4096
#define EMB 1024
#define NB  4
#define TT  4096
#define DD  64

// fold 1/sqrt(64) and log2(e) into Q so softmax runs in exp2 domain
static constexpr float SCALE2 = 0.125f * 1.4426950408889634f;

typedef __bf16          bfrag    __attribute__((ext_vector_type(8)));
typedef float           f32x4    __attribute__((ext_vector_type(4)));
typedef unsigned short  ushort8t __attribute__((ext_vector_type(8)));
typedef unsigned short  ushort4t __attribute__((ext_vector_type(4)));
typedef unsigned int    uint32;
typedef uint32          uint32x4 __attribute__((ext_vector_type(4)));

__device__ __forceinline__ unsigned short f2bf(float f) {
    __hip_bfloat16 h = __float2bfloat16(f);   // RNE
    return __builtin_bit_cast(unsigned short, h);
}
__device__ __forceinline__ float bf2f(unsigned short u) {
    uint32 v = ((uint32)u) << 16;
    return __builtin_bit_cast(float, v);
}
__device__ __forceinline__ uint32 pk2(float a, float b) {
    return (uint32)f2bf(a) | ((uint32)f2bf(b) << 16);
}

// ---------------------------------------------------------------------------
// Prep: Wt[n][k] bf16, n in [0,192) = concat(Wk, Wq*SCALE2, Wv) columns.
// ---------------------------------------------------------------------------
__global__ __launch_bounds__(256) void prep_wt(
    const float* __restrict__ Wk, const float* __restrict__ Wq,
    const float* __restrict__ Wv, unsigned short* __restrict__ Wt)
{
    const int o = blockIdx.x * 256 + threadIdx.x;   // 0 .. 192*1024-1
    const int n = o >> 10, k = o & 1023;
    float v;
    if (n < 64)       v = Wk[k * 64 + n];
    else if (n < 128) v = Wq[k * 64 + (n - 64)] * SCALE2;
    else              v = Wv[k * 64 + (n - 128)];
    Wt[o] = f2bf(v);
}

// ---------------------------------------------------------------------------
// QKV projection (round-4 proven): bf16 MFMA GEMM, M-tile 64, 4 waves, T14
// reg-prefetch of next k-step's emb/W tiles. Outputs Q/K bf16 row-major
// (Q pre-scaled), V^T [b][h][t].
// ---------------------------------------------------------------------------
#define PSTR 66

__global__ __launch_bounds__(256) void qkv_mfma(
    const float* __restrict__ emb,
    const unsigned short* __restrict__ Wt,
    const float* __restrict__ bk, const float* __restrict__ bq,
    const float* __restrict__ bv,
    unsigned short* __restrict__ Qb, unsigned short* __restrict__ Kb,
    unsigned short* __restrict__ Vt)
{
    __shared__ unsigned short elds[64 * PSTR];
    __shared__ unsigned short wlds[192 * PSTR];

    const int tid = threadIdx.x;
    const int w = tid >> 6, l = tid & 63;
    const int lr = l & 15, lg = l >> 4;
    const int m0 = blockIdx.x * 64;

    f32x4 acc[12];
#pragma unroll
    for (int i = 0; i < 12; ++i) acc[i] = (f32x4){0.f, 0.f, 0.f, 0.f};

    const int er = tid >> 2, ec = (tid & 3) * 16;

    float4 f0, f1, f2, f3;
    ushort8t wr[6];
    {   // prologue: load k0 = 0 tiles into regs
        const float* src = emb + (size_t)(m0 + er) * EMB + ec;
        f0 = *(const float4*)(src + 0);
        f1 = *(const float4*)(src + 4);
        f2 = *(const float4*)(src + 8);
        f3 = *(const float4*)(src + 12);
#pragma unroll
        for (int i = 0; i < 6; ++i) {
            const int idx = tid + i * 256;
            const int row = idx >> 3, c = (idx & 7) * 8;
            wr[i] = *(const ushort8t*)&Wt[(size_t)row * 1024 + c];
        }
    }

    for (int it = 0; it < 16; ++it) {
        __syncthreads();   // previous iteration's MFMA reads are done
        {   // write staged regs -> LDS (f32 -> bf16 for emb)
            ushort8t lo, hi;
            lo[0]=f2bf(f0.x); lo[1]=f2bf(f0.y); lo[2]=f2bf(f0.z); lo[3]=f2bf(f0.w);
            lo[4]=f2bf(f1.x); lo[5]=f2bf(f1.y); lo[6]=f2bf(f1.z); lo[7]=f2bf(f1.w);
            hi[0]=f2bf(f2.x); hi[1]=f2bf(f2.y); hi[2]=f2bf(f2.z); hi[3]=f2bf(f2.w);
            hi[4]=f2bf(f3.x); hi[5]=f2bf(f3.y); hi[6]=f2bf(f3.z); hi[7]=f2bf(f3.w);
            *(ushort8t*)&elds[er * PSTR + ec]     = lo;
            *(ushort8t*)&elds[er * PSTR + ec + 8] = hi;
#pragma unroll
            for (int i = 0; i < 6; ++i) {
                const int idx = tid + i * 256;
                const int row = idx >> 3, c = (idx & 7) * 8;
                *(ushort8t*)&wlds[row * PSTR + c] = wr[i];
            }
        }
        // prefetch next k-step into regs (completes under the MFMA phase)
        if (it < 15) {
            const int kn = (it + 1) * 64;
            const float* src = emb + (size_t)(m0 + er) * EMB + kn + ec;
            f0 = *(const float4*)(src + 0);
            f1 = *(const float4*)(src + 4);
            f2 = *(const float4*)(src + 8);
            f3 = *(const float4*)(src + 12);
#pragma unroll
            for (int i = 0; i < 6; ++i) {
                const int idx = tid + i * 256;
                const int row = idx >> 3, c = (idx & 7) * 8;
                wr[i] = *(const ushort8t*)&Wt[(size_t)row * 1024 + kn + c];
            }
        }
        __syncthreads();
#pragma unroll
        for (int c = 0; c < 2; ++c) {
            bfrag a = *(const bfrag*)&elds[(w * 16 + lr) * PSTR + c * 32 + lg * 8];
#pragma unroll
            for (int nt = 0; nt < 12; ++nt) {
                bfrag bb = *(const bfrag*)&wlds[(nt * 16 + lr) * PSTR + c * 32 + lg * 8];
                acc[nt] = __builtin_amdgcn_mfma_f32_16x16x32_bf16(a, bb, acc[nt], 0, 0, 0);
            }
        }
    }

    const int rbase = m0 + w * 16 + lg * 4;
#pragma unroll
    for (int nt = 0; nt < 12; ++nt) {
        const int n = nt * 16 + lr;
        float bias;
        if (n < 64)       bias = bk[n];
        else if (n < 128) bias = bq[n - 64] * SCALE2;
        else              bias = bv[n - 128];
        if (nt < 8) {
            unsigned short* dst = (nt < 4) ? Kb : Qb;
            const int d = (nt < 4) ? n : (n - 64);
#pragma unroll
            for (int rg = 0; rg < 4; ++rg)
                dst[(size_t)(rbase + rg) * 64 + d] = f2bf(acc[nt][rg] + bias);
        } else {
            const int h = n - 128;
            const int b = rbase >> 12, t = rbase & (TT - 1);
            ushort4t pk;
#pragma unroll
            for (int rg = 0; rg < 4; ++rg) pk[rg] = f2bf(acc[nt][rg] + bias);
            *(ushort4t*)&Vt[((size_t)b * 64 + h) * TT + t] = pk;
        }
    }
}

// ---------------------------------------------------------------------------
// Flash attention partials: 1-wave blocks, ZERO LDS, no barriers, split-K.
// Swapped QK^T (S^T = mfma(K,Q)); P redistribution fully in-register via
// dual ds_bpermute + dest-half select (verified round 7).
// ROUND 8 FIX: __launch_bounds__(64, 2) — the (64,4) cap of 128 unified regs
// forced ~170 dwords of scratch spill (WRITE_SIZE 9.8->99.9 MB, 2x dur).
// Live set ~150 regs fits the 256 cap; no spill expected.
// ---------------------------------------------------------------------------
__global__ __launch_bounds__(64, 2) void attn_part(
    const unsigned short* __restrict__ Qb,
    const unsigned short* __restrict__ Kb,
    const unsigned short* __restrict__ Vt,
    unsigned short* __restrict__ po, float* __restrict__ pml,
    int chunk, int nch)
{
    const int idx  = blockIdx.x;
    const int c    = idx >> 9;                    // chunk layer
    const int b    = idx & 3;
    const int ti32 = 127 - ((idx >> 2) & 127);    // heavy-first
    const int nkt  = (ti32 >> 1) + 1;
    const int kt0  = c * chunk;
    if (kt0 >= nkt) return;
    const int kt1 = min(nkt, kt0 + chunk);

    const int l  = threadIdx.x;
    const int lr = l & 15, g = l >> 4;
    const int q0 = ti32 * 32;
    const size_t bTT = (size_t)b * TT;

    // Q fragments (B-operand): lane holds Q[q0+s*16+lr][k=g*8..+7]
    bfrag qa[2][2];
#pragma unroll
    for (int s = 0; s < 2; ++s) {
        const size_t qr = (bTT + q0 + s * 16 + lr) * 64 + g * 8;
        qa[s][0] = *(const bfrag*)&Qb[qr];
        qa[s][1] = *(const bfrag*)&Qb[qr + 32];
    }

    // hoisted pointers (elements); advance by constants per tile
    const unsigned short* kpA = Kb + (bTT + (size_t)kt0 * 64 + lr) * 64 + g * 8;
    const unsigned short* kpB = kpA + 2048;            // nt = 2,3 base
    const unsigned short* vp0 = Vt + ((size_t)b * 64 +  0 + lr) * TT + (size_t)kt0 * 64 + g * 8;
    const unsigned short* vp1 = vp0 + 16 * TT;
    const unsigned short* vp2 = vp0 + 32 * TT;
    const unsigned short* vp3 = vp0 + 48 * TT;

    // bpermute lane addresses (bytes): w2<2 -> lane lr+32*(g&1); w2>=2 -> +16
    const int addr_a = (lr + 32 * (g & 1)) * 4;
    const int addr_b = addr_a + 64;
    const bool ghi = (g >= 2);

    f32x4 o[2][4];
#pragma unroll
    for (int s = 0; s < 2; ++s)
#pragma unroll
        for (int ht = 0; ht < 4; ++ht) o[s][ht] = (f32x4){0.f, 0.f, 0.f, 0.f};
    float mrow[2] = {-1e30f, -1e30f};
    float lrow[2] = {0.f, 0.f};

    for (int kt = kt0; kt < kt1; ++kt) {
        // K fragments (A-operand): K[key=k0+nt*16+lr][k=g*8..]
        bfrag kf[4][2];
        kf[0][0] = *(const bfrag*)(kpA +    0);
        kf[0][1] = *(const bfrag*)(kpA +   32);
        kf[1][0] = *(const bfrag*)(kpA + 1024);
        kf[1][1] = *(const bfrag*)(kpA + 1056);
        kf[2][0] = *(const bfrag*)(kpB +    0);
        kf[2][1] = *(const bfrag*)(kpB +   32);
        kf[3][0] = *(const bfrag*)(kpB + 1024);
        kf[3][1] = *(const bfrag*)(kpB + 1056);
        // V fragments (B-operand for PV): V^T[h=ht*16+lr][k0+cc*32+g*8..]
        bfrag vf[4][2];
        vf[0][0] = *(const bfrag*)(vp0);  vf[0][1] = *(const bfrag*)(vp0 + 32);
        vf[1][0] = *(const bfrag*)(vp1);  vf[1][1] = *(const bfrag*)(vp1 + 32);
        vf[2][0] = *(const bfrag*)(vp2);  vf[2][1] = *(const bfrag*)(vp2 + 32);
        vf[3][0] = *(const bfrag*)(vp3);  vf[3][1] = *(const bfrag*)(vp3 + 32);

        const bool diag = (kt == nkt - 1);
        const int  k0   = kt * 64;

#pragma unroll
        for (int s = 0; s < 2; ++s) {
            // S^T: lane (lr,g) reg rg = S[q0+s*16+lr][k0+nt*16+4g+rg]
            f32x4 sv[4];
#pragma unroll
            for (int nt = 0; nt < 4; ++nt) {
                sv[nt] = (f32x4){0.f, 0.f, 0.f, 0.f};
                sv[nt] = __builtin_amdgcn_mfma_f32_16x16x32_bf16(kf[nt][0], qa[s][0], sv[nt], 0, 0, 0);
                sv[nt] = __builtin_amdgcn_mfma_f32_16x16x32_bf16(kf[nt][1], qa[s][1], sv[nt], 0, 0, 0);
            }
            const int qrow = q0 + s * 16 + lr;
            if (diag) {
#pragma unroll
                for (int nt = 0; nt < 4; ++nt)
#pragma unroll
                    for (int rg = 0; rg < 4; ++rg) {
                        const int key = k0 + nt * 16 + 4 * g + rg;
                        if (key > qrow) sv[nt][rg] = -1e30f;
                    }
            }
            // row max over 16 regs + lanes lr+16k
            float pm = fmaxf(fmaxf(fmaxf(sv[0][0], sv[0][1]), fmaxf(sv[0][2], sv[0][3])),
                             fmaxf(fmaxf(sv[1][0], sv[1][1]), fmaxf(sv[1][2], sv[1][3])));
            pm = fmaxf(pm, fmaxf(fmaxf(fmaxf(sv[2][0], sv[2][1]), fmaxf(sv[2][2], sv[2][3])),
                                 fmaxf(fmaxf(sv[3][0], sv[3][1]), fmaxf(sv[3][2], sv[3][3]))));
            pm = fmaxf(pm, __shfl_xor(pm, 16));
            pm = fmaxf(pm, __shfl_xor(pm, 32));

            // defer-max (T13)
            if (!__all(pm - mrow[s] <= 8.0f)) {
                const float nm = fmaxf(mrow[s], pm);
                const float cr = exp2f(mrow[s] - nm);
                mrow[s] = nm;
                lrow[s] *= cr;
#pragma unroll
                for (int ht = 0; ht < 4; ++ht) o[s][ht] *= cr;
            }

            // P = exp2(S - m) packed bf16 pairs + row sum
            float ls = 0.f;
            uint32 pw[8];
#pragma unroll
            for (int nt = 0; nt < 4; ++nt)
#pragma unroll
                for (int h = 0; h < 2; ++h) {
                    const float pa_ = exp2f(sv[nt][2 * h]     - mrow[s]);
                    const float pb_ = exp2f(sv[nt][2 * h + 1] - mrow[s]);
                    ls += pa_ + pb_;
                    pw[nt * 2 + h] = pk2(pa_, pb_);
                }
            ls += __shfl_xor(ls, 16);
            ls += __shfl_xor(ls, 32);
            lrow[s] += ls;

            // in-register P redistribution -> A-frags (dual bpermute + dest
            // select), then PV
#pragma unroll
            for (int cc = 0; cc < 2; ++cc) {
                uint32x4 dw;
#pragma unroll
                for (int w2 = 0; w2 < 4; ++w2) {
                    const int addr = (w2 < 2) ? addr_a : addr_b;
                    const uint32 lo = (uint32)__builtin_amdgcn_ds_bpermute(
                        addr, (int)pw[4 * cc + (w2 & 1)]);
                    const uint32 hi = (uint32)__builtin_amdgcn_ds_bpermute(
                        addr, (int)pw[4 * cc + 2 + (w2 & 1)]);
                    dw[w2] = ghi ? hi : lo;
                }
                const bfrag pa = __builtin_bit_cast(bfrag, dw);
                o[s][0] = __builtin_amdgcn_mfma_f32_16x16x32_bf16(pa, vf[0][cc], o[s][0], 0, 0, 0);
                o[s][1] = __builtin_amdgcn_mfma_f32_16x16x32_bf16(pa, vf[1][cc], o[s][1], 0, 0, 0);
                o[s][2] = __builtin_amdgcn_mfma_f32_16x16x32_bf16(pa, vf[2][cc], o[s][2], 0, 0, 0);
                o[s][3] = __builtin_amdgcn_mfma_f32_16x16x32_bf16(pa, vf[3][cc], o[s][3], 0, 0, 0);
            }
        }
        kpA += 4096; kpB += 4096;
        vp0 += 64; vp1 += 64; vp2 += 64; vp3 += 64;
    }

    // store partials: po coded C-layout bf16 (coalesced), pml (m,l) f32
    const int slot = (((b << 7) + ti32) * nch) + c;
    const size_t pob = (size_t)slot * 2048;
#pragma unroll
    for (int s = 0; s < 2; ++s)
#pragma unroll
        for (int ht = 0; ht < 4; ++ht)
#pragma unroll
            for (int rg = 0; rg < 4; ++rg)
                po[pob + (size_t)(((s * 4 + ht) * 4 + rg) * 64 + l)] = f2bf(o[s][ht][rg]);
    if (g == 0) {
#pragma unroll
        for (int s = 0; s < 2; ++s) {
            pml[slot * 64 + s * 16 + lr]      = mrow[s];
            pml[slot * 64 + 32 + s * 16 + lr] = lrow[s];
        }
    }
}

// ---------------------------------------------------------------------------
// Merge split-K partials. grid = 512 (one per (b, ti32)), 256 threads; each
// thread owns 8 coded elements (same row, 8 consecutive cols).
// ---------------------------------------------------------------------------
__global__ __launch_bounds__(256) void attn_merge(
    const unsigned short* __restrict__ po, const float* __restrict__ pml,
    float* __restrict__ out, int chunk, int nch)
{
    const int idx  = blockIdx.x;      // 0..511
    const int b    = idx & 3;
    const int ti32 = idx >> 2;
    const int nkt  = (ti32 >> 1) + 1;
    const int nc   = (nkt + chunk - 1) / chunk;

    const int e0   = threadIdx.x * 8;
    const int lane = e0 & 63;
    const int rg   = (e0 >> 6) & 3;
    const int ht   = (e0 >> 8) & 3;
    const int s    = e0 >> 10;
    const int row  = s * 16 + ((lane >> 4) << 2) + rg;
    const int col0 = ht * 16 + (lane & 15);
    const int slot0 = ((b << 7) + ti32) * nch;

    float M = -1e30f;
    for (int c = 0; c < nc; ++c)
        M = fmaxf(M, pml[(slot0 + c) * 64 + row]);

    float den = 0.f;
    float acc[8];
#pragma unroll
    for (int i = 0; i < 8; ++i) acc[i] = 0.f;

    for (int c = 0; c < nc; ++c) {
        const float wgt = exp2f(pml[(slot0 + c) * 64 + row] - M);
        den += wgt * pml[(slot0 + c) * 64 + 32 + row];
        const ushort8t v = *(const ushort8t*)&po[(size_t)(slot0 + c) * 2048 + e0];
#pragma unroll
        for (int j = 0; j < 8; ++j) acc[j] += wgt * bf2f(v[j]);
    }
    const float inv = 1.0f / den;
    float* dst = out + ((size_t)b * TT + ti32 * 32 + row) * 64 + col0;
    float4 o0 = {acc[0] * inv, acc[1] * inv, acc[2] * inv, acc[3] * inv};
    float4 o1 = {acc[4] * inv, acc[5] * inv, acc[6] * inv, acc[7] * inv};
    *(float4*)(dst)     = o0;
    *(float4*)(dst + 4) = o1;
}

// ---------------------------------------------------------------------------
extern "C" void kernel_launch(void* const* d_in, const int* in_sizes, int n_in,
                              void* d_out, int out_size, void* d_ws, size_t ws_size,
                              hipStream_t stream)
{
    const float* emb = (const float*)d_in[0];
    const float* Wk  = (const float*)d_in[1];
    const float* bk  = (const float*)d_in[2];
    const float* Wq  = (const float*)d_in[3];
    const float* bq  = (const float*)d_in[4];
    const float* Wv  = (const float*)d_in[5];
    const float* bv  = (const float*)d_in[6];
    float* out = (float*)d_out;

    // ws: Qb[2MB] Kb[2MB] Vt[2MB] Wt[384KB] | po (bf16) | pml (f32)
    char* base = (char*)d_ws;
    unsigned short* Qb = (unsigned short*)(base);
    unsigned short* Kb = (unsigned short*)(base + (2u << 20));
    unsigned short* Vt = (unsigned short*)(base + (4u << 20));
    unsigned short* Wt = (unsigned short*)(base + (6u << 20));
    const size_t pbase = ((size_t)6 << 20) + (512u << 10);   // 6.5 MB

    int nch = 8;
    for (;;) {
        const size_t need = pbase +
            (size_t)512 * nch * (2048 * sizeof(unsigned short) + 64 * sizeof(float));
        if (need <= ws_size || nch == 1) break;
        nch >>= 1;
    }
    const int chunk = 64 / nch;
    unsigned short* po = (unsigned short*)(base + pbase);
    float* pml = (float*)(po + (size_t)512 * nch * 2048);

    prep_wt<<<192 * 1024 / 256, 256, 0, stream>>>(Wk, Wq, Wv, Wt);
    qkv_mfma<<<(NB * TT) / 64, 256, 0, stream>>>(emb, Wt, bk, bq, bv, Qb, Kb, Vt);
    attn_part<<<512 * nch, 64, 0, stream>>>(Qb, Kb, Vt, po, pml, chunk, nch);
    attn_merge<<<512, 256, 0, stream>>>(po, pml, out, chunk, nch);
}